// Round 14
// baseline (275.559 us; speedup 1.0000x reference)
//
#include <hip/hip_runtime.h>
#include <math.h>

// Problem constants (fixed by reference)
#define B_ 2
#define S_ 2048
#define E_ 1024
#define H_ 16
#define D_ 64
#define M_ (B_ * S_)
// HEAD_DIM * -0.5 = -32 (faithful source bug) folded with 1/ln2 (exp2-domain
// softmax). Folded into Wk at convert time.
#define SC2 (-46.166241308446828f)

typedef unsigned short u16;
typedef _Float16 f16;
typedef __attribute__((ext_vector_type(8))) _Float16 f16x8;   // 4 VGPRs
typedef __attribute__((ext_vector_type(2))) __fp16 fp16x2_n;  // builtin ret type
typedef __attribute__((ext_vector_type(16))) float f32x16;    // 32x32 MFMA acc

static __device__ __forceinline__ f32x16 mfma_h(f16x8 a, f16x8 b, f32x16 c) {
    return __builtin_amdgcn_mfma_f32_32x32x16_f16(a, b, c, 0, 0, 0);
}
static __device__ __forceinline__ u16 f16bits(f16 h) {
    union { f16 h; u16 u; } c; c.h = h; return c.u;
}
static __device__ __forceinline__ unsigned pack2(u16 a, u16 b) {
    return (unsigned)a | ((unsigned)b << 16);
}
// One v_cvt_pkrtz_f16_f32: packs two floats to two fp16 (RTZ; P in [0,1]).
static __device__ __forceinline__ unsigned pkrtz(float a, float b) {
    fp16x2_n h = __builtin_amdgcn_cvt_pkrtz(a, b);
    unsigned u; __builtin_memcpy(&u, &h, 4); return u;
}
// v_permlane32_swap_b32: new a[32:63] = old b[0:31]; new b[0:31] = old a[32:63].
static __device__ __forceinline__ void pl32swap(unsigned &a, unsigned &b) {
    asm volatile("v_permlane32_swap_b32 %0, %1" : "+v"(a), "+v"(b));
}
// T4 counted-vmcnt barrier (R12-proven on the GEMMs). LDS visibility
// (lgkmcnt 0) + rendezvous WITHOUT draining vmcnt: register-destined global
// loads stay in flight across the barrier. R12 lesson: applies to the
// wide-round GEMMs only; attn keeps __syncthreads (T4 regressed it).
static __device__ __forceinline__ void lgkm_bar() {
    asm volatile("s_waitcnt lgkmcnt(0)" ::: "memory");
    __builtin_amdgcn_s_barrier();
}
#define ROWMAP(r, hh) (((r) & 3) + ((((r) >> 2)) << 3) + ((hh) << 2))

// ============================================================================
// One-shot fp32 -> fp16 hi (+ lo-residual where needed). SC2 folded into Wk.
// x, Wk, Wv: hi+lo. Wo: hi only (final GEMM is hi-only).
// ============================================================================
__global__ __launch_bounds__(256)
void convert_split(const float* __restrict__ x, const float* __restrict__ Wk,
                   const float* __restrict__ Wv, const float* __restrict__ Wo,
                   u16* __restrict__ Xh, u16* __restrict__ Xl,
                   u16* __restrict__ Wkh, u16* __restrict__ Wkl,
                   u16* __restrict__ Wvh, u16* __restrict__ Wvl,
                   u16* __restrict__ Woh)
{
    const int blk = blockIdx.x;
    const float* src; u16 *dh, *dl; int base; float sc = 1.0f; bool wantlo = true;
    if (blk < 4096)      { src = x;  dh = Xh;  dl = Xl;  base = blk; }
    else if (blk < 5120) { src = Wk; dh = Wkh; dl = Wkl; base = blk - 4096; sc = SC2; }
    else if (blk < 6144) { src = Wv; dh = Wvh; dl = Wvl; base = blk - 5120; }
    else                 { src = Wo; dh = Woh; dl = Woh; base = blk - 6144; wantlo = false; }
    const size_t off = ((size_t)base * 256 + threadIdx.x) * 4;
    const float4 v = *(const float4*)(src + off);
    const float f[4] = {v.x * sc, v.y * sc, v.z * sc, v.w * sc};
    u16 h4[4], l4[4];
#pragma unroll
    for (int i = 0; i < 4; ++i) {
        const f16 h = (f16)f[i];
        h4[i] = f16bits(h);
        l4[i] = f16bits((f16)(f[i] - (float)h));
    }
    *(uint2*)(dh + off) = make_uint2(pack2(h4[0], h4[1]), pack2(h4[2], h4[3]));
    if (wantlo)
        *(uint2*)(dl + off) = make_uint2(pack2(l4[0], l4[1]), pack2(l4[2], l4[3]));
}

// ============================================================================
// GEMM C = A @ W^T, 32x32x16 fp16 MFMA, hi/lo fp16 inputs.
// R7/R12 model (confirmed): time ~ (# of waitcnt-drain barrier rounds);
// lgkm-only barriers + dbuf cut drains and measurably helped MODE 1.
// R14: MODE 0 A-OPERAND IN REGISTERS — each lane's MFMA A-fragment is a
// per-lane 16B global load (row m0+wm+l31, chunk ch8+4kk); A never needed
// LDS. Staging shrinks 6 -> 4 B-arrays => 2 x 4 x 16.5KB = 132KB dbuf fits
// => ONE lgkm barrier/round, drains 32 -> 16 (the R12 lever applied to
// MODE 0). A-loads strided (2KB/lane) but prefetched a full phase ahead and
// L2-hot (x panel re-read 8x across n-blocks). Same operands, same order ->
// bit-identical numerics.
// MODE 0: fused K+V projection, BK=64, 16 rounds, dbuf 132KB dynamic.
// MODE 1: O @ Wo^T, BK=128, 8 rounds, dbuf 132KB dynamic (R12 state).
// 1024 thr / 16 waves, __launch_bounds__(1024,4). Wave layout: 4m x 2n
// quadrants of 32x64 x 2-way K-SPLIT (ws), fp32 merge via LDS. Grid 256 blk.
// ============================================================================
#define CSB 1032            // (128+1)*8 u16 chunk stride (pad -> spread banks)

template<int MODE>
__global__ __launch_bounds__(1024, 4)
void gemm_f(const u16* __restrict__ Ah_, const u16* __restrict__ Al_,
            const u16* __restrict__ Bkh_, const u16* __restrict__ Bkl_,
            const u16* __restrict__ Bvh_, const u16* __restrict__ Bvl_,
            u16* __restrict__ Khg, u16* __restrict__ Klg,
            u16* __restrict__ Vhg, u16* __restrict__ Vtg,
            float* __restrict__ Cout)
{
    constexpr int BK   = (MODE == 0 ? 64 : 128);
    constexpr int NCH  = BK / 8;                // 8 or 16 chunks
    constexpr int NKK  = NCH / 4;               // 2 or 4 per wave-half
    constexpr int ARRX = NCH * CSB;             // 8256 or 16512 u16
    constexpr int NARR = (MODE == 0 ? 4 : 2);   // staged arrays (B only, MODE 0)
    constexpr int BUFS = NARR * ARRX;           // one buffer: 33024 u16 both
    constexpr int NIT  = E_ / BK;               // 16 or 8
    extern __shared__ u16 stage[];              // 2 x BUFS = 132KB dynamic

    const int tid = threadIdx.x;
    const int w = tid >> 6, l31 = tid & 31, hh = (tid >> 5) & 1;
    const int wt = w & 7, ws = w >> 3;          // 4m x 2n quadrant / k-split half
    const int wm = (wt >> 1) << 5, wn = (wt & 1) << 6;
    const int m0 = blockIdx.y * 128, n0 = blockIdx.x * 128;
    const int ch8 = (ws << 1) + hh;             // wave-half's base k-subchunk

    // staging: rows 0..127 (tid>>3), chunks 0..7 (tid&7); MODE 1 also +8.
    const int sr = tid >> 3, sch = tid & 7;
    const size_t gA = (size_t)(m0 + sr) * E_ + (sch << 3);
    const size_t gB = (size_t)(n0 + sr) * E_ + (sch << 3);
    const int slo = sch * CSB + sr * 8;
    const size_t aRow = (size_t)(m0 + wm + l31) * E_;   // MODE 0 A-frag row

    f32x16 acc1[2], acc2[2];
#pragma unroll
    for (int nt = 0; nt < 2; ++nt)
#pragma unroll
        for (int r = 0; r < 16; ++r) {
            acc1[nt][r] = 0.f;
            if constexpr (MODE == 0) acc2[nt][r] = 0.f;
        }

    f16x8 pf0[4], pf1[4];               // staged-array prefetch (B arrays)
    f16x8 axA[4], axB[4];               // MODE 0: A-fragments (xh0,xh1,xl0,xl1)
    auto load_tile = [&](int k0, f16x8* pf) {
        if constexpr (MODE == 0) {
            pf[0] = *(const f16x8*)(Bkh_ + gB + k0);
            pf[1] = *(const f16x8*)(Bkl_ + gB + k0);
            pf[2] = *(const f16x8*)(Bvh_ + gB + k0);
            pf[3] = *(const f16x8*)(Bvl_ + gB + k0);
        } else {
            pf[0] = *(const f16x8*)(Ah_ + gA + k0);
            pf[1] = *(const f16x8*)(Ah_ + gA + k0 + 64);
            pf[2] = *(const f16x8*)(Bkh_ + gB + k0);
            pf[3] = *(const f16x8*)(Bkh_ + gB + k0 + 64);
        }
    };
    auto load_a = [&](int k0, f16x8* ax) {      // MODE 0 only
        ax[0] = *(const f16x8*)(Ah_ + aRow + k0 + (ch8 << 3));
        ax[1] = *(const f16x8*)(Ah_ + aRow + k0 + ((ch8 + 4) << 3));
        ax[2] = *(const f16x8*)(Al_ + aRow + k0 + (ch8 << 3));
        ax[3] = *(const f16x8*)(Al_ + aRow + k0 + ((ch8 + 4) << 3));
    };
    auto store_tile = [&](int bb, f16x8* pf) {  // bb = buffer base (u16 elems)
        if constexpr (MODE == 0) {
#pragma unroll
            for (int a = 0; a < 4; ++a)
                *(f16x8*)&stage[bb + a * ARRX + slo] = pf[a];
        } else {
            *(f16x8*)&stage[bb + slo] = pf[0];
            *(f16x8*)&stage[bb + (sch + 8) * CSB + sr * 8] = pf[1];
            *(f16x8*)&stage[bb + ARRX + slo] = pf[2];
            *(f16x8*)&stage[bb + ARRX + (sch + 8) * CSB + sr * 8] = pf[3];
        }
    };
    auto compute0 = [&](int bb, const f16x8* ax) {   // MODE 0: A from regs
#pragma unroll
        for (int kk = 0; kk < 2; ++kk) {
            const int co = bb + (ch8 + (kk << 2)) * CSB;
            const f16x8 xh = ax[kk], xl = ax[2 + kk];
#pragma unroll
            for (int nt = 0; nt < 2; ++nt) {
                const int rb = co + (wn + (nt << 5) + l31) * 8;
                const f16x8 bkh = *(const f16x8*)&stage[rb + 0 * ARRX];
                const f16x8 bkl = *(const f16x8*)&stage[rb + 1 * ARRX];
                const f16x8 bvh = *(const f16x8*)&stage[rb + 2 * ARRX];
                const f16x8 bvl = *(const f16x8*)&stage[rb + 3 * ARRX];
                acc1[nt] = mfma_h(xh, bkh, acc1[nt]);
                acc1[nt] = mfma_h(xh, bkl, acc1[nt]);
                acc1[nt] = mfma_h(xl, bkh, acc1[nt]);
                acc2[nt] = mfma_h(xh, bvh, acc2[nt]);
                acc2[nt] = mfma_h(xh, bvl, acc2[nt]);
                acc2[nt] = mfma_h(xl, bvh, acc2[nt]);
            }
        }
    };
    auto compute1 = [&](int bb) {                    // MODE 1: A from LDS
#pragma unroll
        for (int kk = 0; kk < NKK; ++kk) {
            const int co = bb + (ch8 + (kk << 2)) * CSB;
            const f16x8 xh = *(const f16x8*)&stage[co + (wm + l31) * 8];
#pragma unroll
            for (int nt = 0; nt < 2; ++nt) {
                const int ro = co + (wn + (nt << 5) + l31) * 8;
                const f16x8 bh = *(const f16x8*)&stage[ARRX + ro];
                acc1[nt] = mfma_h(xh, bh, acc1[nt]);
            }
        }
    };

    // Double-buffered, one lgkm barrier per round (both modes).
    load_tile(0, pf0);
    if constexpr (MODE == 0) load_a(0, axA);
    store_tile(0, pf0);                 // prologue vmcnt wait (once)
    load_tile(BK, pf1);
    if constexpr (MODE == 0) load_a(BK, axB);
    lgkm_bar();
    for (int p = 0; p < NIT / 2; ++p) {
        const int e = 2 * p;
        if (e + 2 < NIT) load_tile((e + 2) * BK, pf0);
        if constexpr (MODE == 0) {
            compute0(0, axA);                       // tile e (A regs tile e)
            if (e + 2 < NIT) load_a((e + 2) * BK, axA);  // after consumption
        } else {
            compute1(0);
        }
        store_tile(BUFS, pf1);                      // tile e+1 -> buf1
        lgkm_bar();
        if (e + 3 < NIT) load_tile((e + 3) * BK, pf1);
        if constexpr (MODE == 0) {
            compute0(BUFS, axB);                    // tile e+1
            if (e + 3 < NIT) load_a((e + 3) * BK, axB);
        } else {
            compute1(BUFS);
        }
        if (e + 2 < NIT) store_tile(0, pf0);        // tile e+2 -> buf0
        lgkm_bar();
    }

    // K-split merge via LDS (32KB rounds: one (array,nt) per round), ws1 -> ws0.
    // __syncthreads (full drain) here: cold path, safety first.
    float* red = (float*)stage;
    constexpr int NR = (MODE == 0 ? 4 : 2);
#pragma unroll
    for (int rd = 0; rd < NR; ++rd) {
        const int ntr = rd & 1;
        f32x16* A = (MODE == 0 && rd >= 2) ? &acc2[ntr] : &acc1[ntr];
        __syncthreads();
        if (ws == 1) {
#pragma unroll
            for (int r = 0; r < 16; ++r)
                red[(wt << 10) + (r << 6) + (hh << 5) + l31] = (*A)[r];
        }
        __syncthreads();
        if (ws == 0) {
#pragma unroll
            for (int r = 0; r < 16; ++r)
                (*A)[r] += red[(wt << 10) + (r << 6) + (hh << 5) + l31];
        }
    }
    if (ws != 0) return;

    // Epilogue (ws0, 8 waves cover 128x128). C/D map: col=lane&31, row=ROWMAP.
#pragma unroll
    for (int nt = 0; nt < 2; ++nt) {
        const int n = n0 + wn + (nt << 5) + l31;
        if constexpr (MODE == 1) {
#pragma unroll
            for (int r = 0; r < 16; ++r) {
                const int m = m0 + wm + ROWMAP(r, hh);
                Cout[(size_t)m * E_ + n] = acc1[nt][r];
            }
        } else {
            const int hd = n >> 6, d = n & 63;
            const int b = m0 >> 11;             // block never crosses batch
            u16 vb16[16];
#pragma unroll
            for (int r = 0; r < 16; ++r) {
                const int s = (m0 + wm + ROWMAP(r, hh)) & (S_ - 1);
                const size_t ib = (((size_t)(b * H_ + hd) << 11) + s) * D_ + d;
                const float kv = acc1[nt][r];   // SC2 already folded
                const f16 kh = (f16)kv;
                Khg[ib] = f16bits(kh);
                Klg[ib] = f16bits((f16)(kv - (float)kh));
                const f16 vh = (f16)acc2[nt][r];
                vb16[r] = f16bits(vh);
                Vhg[ib] = vb16[r];
            }
            const size_t vtb = ((size_t)(b * H_ + hd) * D_ + d) << 11;
#pragma unroll
            for (int g = 0; g < 4; ++g) {
                const int s0 = ((m0 + wm) & (S_ - 1)) + (g << 3) + (hh << 2);
                *(uint2*)&Vtg[vtb + s0] =
                    make_uint2(pack2(vb16[4 * g], vb16[4 * g + 1]),
                               pack2(vb16[4 * g + 2], vb16[4 * g + 3]));
            }
        }
    }
}

// ============================================================================
// Attention (R3/R10-exact, best measured 65.0-65.8us; FROZEN).
// Session evidence: T15 interleave (R4, -4%), pair-rounds (R8, 0), indep.
// blocks (R9, 0), t-splits (R2/R6, negative), counted-vmcnt pipeline (R12,
// -7%) — all rearrangements land 65-69us. The dependent chain (ds_read ->
// St MFMA -> softmax VALU -> PV MFMA) at 2 waves/SIMD is the structural
// floor; __syncthreads' vmcnt drain is NOT the cost (R12 refuted).
// logits2 = Ks@V^T, base-2 online softmax, O = P@V. All fp16.
// 512 thr / 8 waves; 256 s-rows/block; grid (8,32)=256 blocks.
// O^T orientation: PV computes D[m=d][n=s], A = Vt (staged), B = P^T built
// in-register via 16 cvt_pkrtz + 8 v_permlane32_swap_b32 (T12); per-lane
// alpha/linv. sV double-buffered (2 x [Vh|Vt] = 33.3KB static), depth-1
// register prefetch, 1 barrier/iter.
// ============================================================================
#define CSA 520             // (64+1)*8 u16
#define VA  (8 * CSA)       // one V array: 4160 u16

__global__ __launch_bounds__(512, 2)
void attn_mfma(const u16* __restrict__ Kh, const u16* __restrict__ Kl,
               const u16* __restrict__ Vh, const u16* __restrict__ Vt,
               u16* __restrict__ Obuf)
{
    __shared__ u16 sV[4 * VA];          // [buf][Vh | Vt], double-buffered

    const int tid = threadIdx.x;
    const int w = tid >> 6, l31 = tid & 31, hh = (tid >> 5) & 1;
    const int bh = blockIdx.y;
    const int sbase = blockIdx.x * 256 + (w << 5);
    const int sg = sbase + l31;

    // K fragments (SC2 pre-folded): B[n=s][k=d], hi/lo, loop-invariant
    f16x8 kfh[4], kfl[4];
    {
        const size_t kb = ((size_t)bh * S_ + sg) * D_;
#pragma unroll
        for (int ks = 0; ks < 4; ++ks) {
            const int db = (ks << 4) + (hh << 3);
            kfh[ks] = *(const f16x8*)(Kh + kb + db);
            kfl[ks] = *(const f16x8*)(Kl + kb + db);
        }
    }

    f32x16 oacc[2];                     // O^T: row d = ROWMAP+32nt, col s = l31
#pragma unroll
    for (int r = 0; r < 16; ++r) { oacc[0][r] = 0.f; oacc[1][r] = 0.f; }
    float m_i = -INFINITY, l_i = 0.f;

    const int rr = tid >> 3, cc = tid & 7;     // staging: row 0..63, chunk 0..7
    const size_t gn = ((size_t)bh * S_ + rr) * D_ + (cc << 3);
    const size_t gt = ((size_t)bh * D_ + rr) * S_ + (cc << 3);
    const int slo = cc * CSA + rr * 8;

    f16x8 pv[2];
    auto load_tile = [&](int it2) {
        const size_t t0 = (size_t)it2 << 6;
        pv[0] = *(const f16x8*)(Vh + gn + t0 * D_);
        pv[1] = *(const f16x8*)(Vt + gt + t0);
    };

    load_tile(0);
    *(f16x8*)&sV[slo] = pv[0];
    *(f16x8*)&sV[VA + slo] = pv[1];
    __syncthreads();

    for (int it = 0; it < 32; ++it) {
        const int vb = (it & 1) * (2 * VA);
        const int nb = ((it + 1) & 1) * (2 * VA);
        if (it + 1 < 32) load_tile(it + 1);    // global->reg prefetch

        // St[t][s] = sum_d V[t][d]*Ks[s][d]  (2-pass, dual chains)
        f32x16 sta[2], stb[2];
#pragma unroll
        for (int r = 0; r < 16; ++r) {
            sta[0][r] = 0.f; sta[1][r] = 0.f;
            stb[0][r] = 0.f; stb[1][r] = 0.f;
        }
#pragma unroll
        for (int ks = 0; ks < 4; ++ks) {
            const int ch = (ks << 1) + hh;
#pragma unroll
            for (int mt = 0; mt < 2; ++mt) {
                const f16x8 av = *(const f16x8*)&sV[vb + ch * CSA + ((mt << 5) + l31) * 8];
                sta[mt] = mfma_h(av, kfh[ks], sta[mt]);
                stb[mt] = mfma_h(av, kfl[ks], stb[mt]);
            }
        }
#pragma unroll
        for (int mt = 0; mt < 2; ++mt)
#pragma unroll
            for (int r = 0; r < 16; ++r) sta[mt][r] += stb[mt][r];

        // Online softmax (base 2) over t for col s = l31
        float tmax = -INFINITY;
#pragma unroll
        for (int mt = 0; mt < 2; ++mt)
#pragma unroll
            for (int r = 0; r < 16; ++r) tmax = fmaxf(tmax, sta[mt][r]);
        tmax = fmaxf(tmax, __shfl_xor(tmax, 32));
        const float mnew = fmaxf(m_i, tmax);
        const float alpha = __builtin_amdgcn_exp2f(m_i - mnew);  // first tile: 0
        m_i = mnew;
        // cmask==0  =>  mnew==m_i for every lane  =>  alpha==1: skip all.
        const unsigned long long cmask = __ballot(tmax >= mnew - 30.f);

        if (cmask) {
            float rsum = 0.f;
#pragma unroll
            for (int mt = 0; mt < 2; ++mt)
#pragma unroll
                for (int r = 0; r < 16; ++r) {
                    const float p = __builtin_amdgcn_exp2f(sta[mt][r] - mnew);
                    sta[mt][r] = p;
                    rsum += p;
                }
            rsum += __shfl_xor(rsum, 32);
            l_i = l_i * alpha + rsum;

            // alpha rescale: per-lane (oacc col = s = l31)
#pragma unroll
            for (int r = 0; r < 16; ++r) { oacc[0][r] *= alpha; oacc[1][r] *= alpha; }

            // pack P to fp16: pa[mt][q] = (t0,t0+1), pb = (t0+2,t0+3),
            // t0 = 32mt+8q+4hh (own hh)
            unsigned pa[2][4], pb[2][4];
#pragma unroll
            for (int mt = 0; mt < 2; ++mt)
#pragma unroll
                for (int q = 0; q < 4; ++q) {
                    pa[mt][q] = pkrtz(sta[mt][4 * q + 0], sta[mt][4 * q + 1]);
                    pb[mt][q] = pkrtz(sta[mt][4 * q + 2], sta[mt][4 * q + 3]);
                }

            // PV: O^T[d][s] += Vt[d][t] * P^T[t][s], 4 chunks of K=16
#pragma unroll
            for (int ks = 0; ks < 4; ++ks) {
                const int mt = ks >> 1, kk = ks & 1;
                unsigned w0 = pa[mt][2 * kk], w2v = pa[mt][2 * kk + 1];
                pl32swap(w0, w2v);
                unsigned w1 = pb[mt][2 * kk], w3v = pb[mt][2 * kk + 1];
                pl32swap(w1, w3v);
                union { unsigned u[4]; f16x8 v; } bw;
                bw.u[0] = w0; bw.u[1] = w1; bw.u[2] = w2v; bw.u[3] = w3v;
                const int ch = (ks << 1) + hh;
#pragma unroll
                for (int nt = 0; nt < 2; ++nt) {
                    const f16x8 vtf = *(const f16x8*)&sV[vb + VA + ch * CSA + ((nt << 5) + l31) * 8];
                    oacc[nt] = mfma_h(vtf, bw.v, oacc[nt]);
                }
            }
        }

        if (it + 1 < 32) {                     // stage next tile into other buf
            *(f16x8*)&sV[nb + slo] = pv[0];
            *(f16x8*)&sV[nb + VA + slo] = pv[1];
        }
        __syncthreads();
    }

    // Epilogue: per-lane normalize (l_i is per-s = per-lane), store O fp16 [M,E]
    const float linv = (l_i > 0.f) ? (1.0f / l_i) : 0.f;
    const int b = bh >> 4;
    const int hd = bh & 15;
    u16* Or = Obuf + ((size_t)b * S_ + sg) * E_ + (hd << 6);
#pragma unroll
    for (int nt = 0; nt < 2; ++nt)
#pragma unroll
        for (int q = 0; q < 4; ++q) {
            const int d0 = (nt << 5) + (q << 3) + (hh << 2);
            u16 c[4];
#pragma unroll
            for (int j = 0; j < 4; ++j)
                c[j] = f16bits((f16)(oacc[nt][4 * q + j] * linv));
            *(uint2*)&Or[d0] = make_uint2(pack2(c[0], c[1]), pack2(c[2], c[3]));
        }
}

// ============================================================================
// Workspace (~58 MB):
//   0M Xh | 8M Xl (aliased by Obuf after gemm_kv) | 16M Wkh | 18M Wkl
//   20M Wvh | 22M Wvl | 24M Woh | 26M Kh | 34M Kl | 42M Vh | 50M Vt
// ============================================================================
extern "C" void kernel_launch(void* const* d_in, const int* in_sizes, int n_in,
                              void* d_out, int out_size, void* d_ws, size_t ws_size,
                              hipStream_t stream)
{
    (void)in_sizes; (void)n_in; (void)out_size; (void)ws_size;
    const float* x  = (const float*)d_in[0];
    // d_in[1] = Wq: computed-but-unused in reference; skipped.
    const float* Wk = (const float*)d_in[2];
    const float* Wv = (const float*)d_in[3];
    const float* Wo = (const float*)d_in[4];
    float* out = (float*)d_out;

    char* ws = (char*)d_ws;
    const size_t MB = 1u << 20;
    u16* Xh  = (u16*)(ws + 0 * MB);
    u16* Xl  = (u16*)(ws + 8 * MB);
    u16* Wkh = (u16*)(ws + 16 * MB);
    u16* Wkl = (u16*)(ws + 18 * MB);
    u16* Wvh = (u16*)(ws + 20 * MB);
    u16* Wvl = (u16*)(ws + 22 * MB);
    u16* Woh = (u16*)(ws + 24 * MB);
    u16* Kh  = (u16*)(ws + 26 * MB);
    u16* Kl  = (u16*)(ws + 34 * MB);
    u16* Vh  = (u16*)(ws + 42 * MB);
    u16* Vt  = (u16*)(ws + 50 * MB);
    u16* Obuf = Xl;        // x-lo dead after gemm_kv

    // Dynamic-LDS sizes (gemms only; attn is static 33.3KB).
    const int lds0 = 2 * 4 * (8 * CSB) * (int)sizeof(u16);    // 132096 B (dbuf)
    const int lds1 = 2 * 2 * (16 * CSB) * (int)sizeof(u16);   // 132096 B (dbuf)
    static bool attr_done = false;
    if (!attr_done) {
        hipFuncSetAttribute(reinterpret_cast<const void*>(&gemm_f<0>),
                            hipFuncAttributeMaxDynamicSharedMemorySize, lds0);
        hipFuncSetAttribute(reinterpret_cast<const void*>(&gemm_f<1>),
                            hipFuncAttributeMaxDynamicSharedMemorySize, lds1);
        attr_done = true;
    }

    convert_split<<<7168, 256, 0, stream>>>(x, Wk, Wv, Wo,
                                            Xh, Xl, Wkh, Wkl, Wvh, Wvl, Woh);
    gemm_f<0><<<dim3(E_ / 128, M_ / 128), 1024, lds0, stream>>>(
        Xh, Xl, Wkh, Wkl, Wvh, Wvl, Kh, Kl, Vh, Vt, nullptr);
    attn_mfma<<<dim3(S_ / 256, B_ * H_), 512, 0, stream>>>(Kh, Kl, Vh, Vt, Obuf);
    gemm_f<1><<<dim3(E_ / 128, M_ / 128), 1024, lds1, stream>>>(
        Obuf, Obuf, Woh, Woh, Woh, Woh,
        nullptr, nullptr, nullptr, nullptr, out);
}

// Round 15
// 215.060 us; speedup vs baseline: 1.2813x; 1.2813x over previous
//
#include <hip/hip_runtime.h>
#include <math.h>

// Problem constants (fixed by reference)
#define B_ 2
#define S_ 2048
#define E_ 1024
#define H_ 16
#define D_ 64
#define M_ (B_ * S_)
// HEAD_DIM * -0.5 = -32 (faithful source bug) folded with 1/ln2 (exp2-domain
// softmax). Folded into Wk at convert time.
#define SC2 (-46.166241308446828f)

typedef unsigned short u16;
typedef _Float16 f16;
typedef __attribute__((ext_vector_type(8))) _Float16 f16x8;   // 4 VGPRs
typedef __attribute__((ext_vector_type(2))) __fp16 fp16x2_n;  // builtin ret type
typedef __attribute__((ext_vector_type(16))) float f32x16;    // 32x32 MFMA acc

static __device__ __forceinline__ f32x16 mfma_h(f16x8 a, f16x8 b, f32x16 c) {
    return __builtin_amdgcn_mfma_f32_32x32x16_f16(a, b, c, 0, 0, 0);
}
static __device__ __forceinline__ u16 f16bits(f16 h) {
    union { f16 h; u16 u; } c; c.h = h; return c.u;
}
static __device__ __forceinline__ unsigned pack2(u16 a, u16 b) {
    return (unsigned)a | ((unsigned)b << 16);
}
// One v_cvt_pkrtz_f16_f32: packs two floats to two fp16 (RTZ; P in [0,1]).
static __device__ __forceinline__ unsigned pkrtz(float a, float b) {
    fp16x2_n h = __builtin_amdgcn_cvt_pkrtz(a, b);
    unsigned u; __builtin_memcpy(&u, &h, 4); return u;
}
// v_permlane32_swap_b32: new a[32:63] = old b[0:31]; new b[0:31] = old a[32:63].
static __device__ __forceinline__ void pl32swap(unsigned &a, unsigned &b) {
    asm volatile("v_permlane32_swap_b32 %0, %1" : "+v"(a), "+v"(b));
}
// T4 counted-vmcnt barrier (R12-proven on the GEMMs: total-attn -10us).
// LDS visibility (lgkmcnt 0) + rendezvous WITHOUT draining vmcnt:
// register-destined global loads stay in flight across the barrier.
// R12 lesson: applies to the wide-round GEMMs only; attn keeps
// __syncthreads (T4 regressed it). R14 lesson: depth-2 prefetch + extra
// register state must pass the static live-reg budget vs the launch_bounds
// cap (MODE 0 at 128-cap spilled 280MB; reverted to single-buffer).
static __device__ __forceinline__ void lgkm_bar() {
    asm volatile("s_waitcnt lgkmcnt(0)" ::: "memory");
    __builtin_amdgcn_s_barrier();
}
#define ROWMAP(r, hh) (((r) & 3) + ((((r) >> 2)) << 3) + ((hh) << 2))

// ============================================================================
// One-shot fp32 -> fp16 hi (+ lo-residual where needed). SC2 folded into Wk.
// x, Wk, Wv: hi+lo. Wo: hi only (final GEMM is hi-only).
// ============================================================================
__global__ __launch_bounds__(256)
void convert_split(const float* __restrict__ x, const float* __restrict__ Wk,
                   const float* __restrict__ Wv, const float* __restrict__ Wo,
                   u16* __restrict__ Xh, u16* __restrict__ Xl,
                   u16* __restrict__ Wkh, u16* __restrict__ Wkl,
                   u16* __restrict__ Wvh, u16* __restrict__ Wvl,
                   u16* __restrict__ Woh)
{
    const int blk = blockIdx.x;
    const float* src; u16 *dh, *dl; int base; float sc = 1.0f; bool wantlo = true;
    if (blk < 4096)      { src = x;  dh = Xh;  dl = Xl;  base = blk; }
    else if (blk < 5120) { src = Wk; dh = Wkh; dl = Wkl; base = blk - 4096; sc = SC2; }
    else if (blk < 6144) { src = Wv; dh = Wvh; dl = Wvl; base = blk - 5120; }
    else                 { src = Wo; dh = Woh; dl = Woh; base = blk - 6144; wantlo = false; }
    const size_t off = ((size_t)base * 256 + threadIdx.x) * 4;
    const float4 v = *(const float4*)(src + off);
    const float f[4] = {v.x * sc, v.y * sc, v.z * sc, v.w * sc};
    u16 h4[4], l4[4];
#pragma unroll
    for (int i = 0; i < 4; ++i) {
        const f16 h = (f16)f[i];
        h4[i] = f16bits(h);
        l4[i] = f16bits((f16)(f[i] - (float)h));
    }
    *(uint2*)(dh + off) = make_uint2(pack2(h4[0], h4[1]), pack2(h4[2], h4[3]));
    if (wantlo)
        *(uint2*)(dl + off) = make_uint2(pack2(l4[0], l4[1]), pack2(l4[2], l4[3]));
}

// ============================================================================
// GEMM C = A @ W^T, 32x32x16 fp16 MFMA, hi/lo fp16 inputs.  (R12-proven
// state — best measured total 209.4us; R14's A-in-regs variant spilled and
// was reverted.)
// MODE 0: fused K+V projection, BK=64, 6 arrays = 99KB dynamic LDS,
//         single-buffered (2x99KB > 160KB), depth-1 reg prefetch,
//         lgkm-only barriers (loads stay in flight).
// MODE 1: O @ Wo^T, BK=128, 2 arrays x 2 LDS buffers = 132KB dynamic,
//         depth-2 parity reg prefetch (pf0/pf1, static indexing) -> each
//         round's ds_write waits a COUNTED vmcnt with ~2-round window.
// 1024 thr / 16 waves, __launch_bounds__(1024,4). Wave layout: 4m x 2n
// quadrants of 32x64 x 2-way K-SPLIT (ws), fp32 merge via LDS. Grid 256 blk.
// ============================================================================
#define CSB 1032            // (128+1)*8 u16 chunk stride (pad -> spread banks)

template<int MODE>
__global__ __launch_bounds__(1024, 4)
void gemm_f(const u16* __restrict__ Ah_, const u16* __restrict__ Al_,
            const u16* __restrict__ Bkh_, const u16* __restrict__ Bkl_,
            const u16* __restrict__ Bvh_, const u16* __restrict__ Bvl_,
            u16* __restrict__ Khg, u16* __restrict__ Klg,
            u16* __restrict__ Vhg, u16* __restrict__ Vtg,
            float* __restrict__ Cout)
{
    constexpr int BK   = (MODE == 0 ? 64 : 128);
    constexpr int NCH  = BK / 8;                // 8 or 16 chunks
    constexpr int NKK  = NCH / 4;               // 2 or 4 per wave-half
    constexpr int ARRX = NCH * CSB;             // 8256 or 16512 u16
    constexpr int NIT  = E_ / BK;               // 16 or 8
    extern __shared__ u16 stage[];              // 99KB / 132KB dynamic

    const int tid = threadIdx.x;
    const int w = tid >> 6, l31 = tid & 31, hh = (tid >> 5) & 1;
    const int wt = w & 7, ws = w >> 3;          // 4m x 2n quadrant / k-split half
    const int wm = (wt >> 1) << 5, wn = (wt & 1) << 6;
    const int m0 = blockIdx.y * 128, n0 = blockIdx.x * 128;
    const int ch8 = (ws << 1) + hh;             // wave-half's base k-subchunk

    // staging: rows 0..127 (tid>>3), chunks 0..7 (tid&7); MODE 1 also +8.
    const int sr = tid >> 3, sch = tid & 7;
    const size_t gA = (size_t)(m0 + sr) * E_ + (sch << 3);
    const size_t gB = (size_t)(n0 + sr) * E_ + (sch << 3);
    const int slo = sch * CSB + sr * 8;

    f32x16 acc1[2], acc2[2];
#pragma unroll
    for (int nt = 0; nt < 2; ++nt)
#pragma unroll
        for (int r = 0; r < 16; ++r) {
            acc1[nt][r] = 0.f;
            if constexpr (MODE == 0) acc2[nt][r] = 0.f;
        }

    constexpr int NPF = (MODE == 0 ? 6 : 4);
    f16x8 pf0[NPF], pf1[NPF];
    auto load_tile = [&](int k0, f16x8* pf) {
        if constexpr (MODE == 0) {
            pf[0] = *(const f16x8*)(Ah_ + gA + k0);
            pf[1] = *(const f16x8*)(Al_ + gA + k0);
            pf[2] = *(const f16x8*)(Bkh_ + gB + k0);
            pf[3] = *(const f16x8*)(Bkl_ + gB + k0);
            pf[4] = *(const f16x8*)(Bvh_ + gB + k0);
            pf[5] = *(const f16x8*)(Bvl_ + gB + k0);
        } else {
            pf[0] = *(const f16x8*)(Ah_ + gA + k0);
            pf[1] = *(const f16x8*)(Ah_ + gA + k0 + 64);
            pf[2] = *(const f16x8*)(Bkh_ + gB + k0);
            pf[3] = *(const f16x8*)(Bkh_ + gB + k0 + 64);
        }
    };
    auto store_tile = [&](int bb, f16x8* pf) {  // bb = buffer base (u16 elems)
        if constexpr (MODE == 0) {
#pragma unroll
            for (int a = 0; a < 6; ++a)
                *(f16x8*)&stage[bb + a * ARRX + slo] = pf[a];
        } else {
            *(f16x8*)&stage[bb + slo] = pf[0];
            *(f16x8*)&stage[bb + (sch + 8) * CSB + sr * 8] = pf[1];
            *(f16x8*)&stage[bb + ARRX + slo] = pf[2];
            *(f16x8*)&stage[bb + ARRX + (sch + 8) * CSB + sr * 8] = pf[3];
        }
    };
    auto compute = [&](int bb) {
#pragma unroll
        for (int kk = 0; kk < NKK; ++kk) {
            const int co = bb + (ch8 + (kk << 2)) * CSB;
            const int offx = co + (wm + l31) * 8;
            const f16x8 xh = *(const f16x8*)&stage[0 * ARRX + offx];
            f16x8 xl;
            if constexpr (MODE == 0) xl = *(const f16x8*)&stage[1 * ARRX + offx];
#pragma unroll
            for (int nt = 0; nt < 2; ++nt) {
                const int ro = co + (wn + (nt << 5) + l31) * 8;
                if constexpr (MODE == 0) {
                    const f16x8 bkh = *(const f16x8*)&stage[2 * ARRX + ro];
                    const f16x8 bkl = *(const f16x8*)&stage[3 * ARRX + ro];
                    const f16x8 bvh = *(const f16x8*)&stage[4 * ARRX + ro];
                    const f16x8 bvl = *(const f16x8*)&stage[5 * ARRX + ro];
                    acc1[nt] = mfma_h(xh, bkh, acc1[nt]);
                    acc1[nt] = mfma_h(xh, bkl, acc1[nt]);
                    acc1[nt] = mfma_h(xl, bkh, acc1[nt]);
                    acc2[nt] = mfma_h(xh, bvh, acc2[nt]);
                    acc2[nt] = mfma_h(xh, bvl, acc2[nt]);
                    acc2[nt] = mfma_h(xl, bvh, acc2[nt]);
                } else {
                    const f16x8 bh = *(const f16x8*)&stage[ARRX + ro];
                    acc1[nt] = mfma_h(xh, bh, acc1[nt]);
                }
            }
        }
    };

    if constexpr (MODE == 0) {
        // Single-buffered; lgkm-only barriers keep load(it+1) in flight
        // across the post-compute barrier (its wait lands at next store).
        load_tile(0, pf0);
        for (int it = 0; it < NIT; ++it) {
            store_tile(0, pf0);
            lgkm_bar();
            if (it + 1 < NIT) load_tile((it + 1) * BK, pf0);
            compute(0);
            lgkm_bar();
        }
    } else {
        // Double-buffered, depth-2 parity prefetch, one lgkm barrier/round.
        load_tile(0, pf0);
        store_tile(0, pf0);            // prologue vmcnt wait (once)
        load_tile(BK, pf1);
        lgkm_bar();
        for (int p = 0; p < NIT / 2; ++p) {
            const int e = 2 * p;
            if (e + 2 < NIT) load_tile((e + 2) * BK, pf0);
            compute(0);
            store_tile(2 * ARRX, pf1);             // tile e+1 -> buf1
            lgkm_bar();
            if (e + 3 < NIT) load_tile((e + 3) * BK, pf1);
            compute(2 * ARRX);
            if (e + 2 < NIT) store_tile(0, pf0);   // tile e+2 -> buf0
            lgkm_bar();
        }
    }

    // K-split merge via LDS (32KB rounds: one (array,nt) per round), ws1 -> ws0.
    // __syncthreads (full drain) here: cold path, safety first.
    float* red = (float*)stage;
    constexpr int NR = (MODE == 0 ? 4 : 2);
#pragma unroll
    for (int rd = 0; rd < NR; ++rd) {
        const int ntr = rd & 1;
        f32x16* A = (MODE == 0 && rd >= 2) ? &acc2[ntr] : &acc1[ntr];
        __syncthreads();
        if (ws == 1) {
#pragma unroll
            for (int r = 0; r < 16; ++r)
                red[(wt << 10) + (r << 6) + (hh << 5) + l31] = (*A)[r];
        }
        __syncthreads();
        if (ws == 0) {
#pragma unroll
            for (int r = 0; r < 16; ++r)
                (*A)[r] += red[(wt << 10) + (r << 6) + (hh << 5) + l31];
        }
    }
    if (ws != 0) return;

    // Epilogue (ws0, 8 waves cover 128x128). C/D map: col=lane&31, row=ROWMAP.
#pragma unroll
    for (int nt = 0; nt < 2; ++nt) {
        const int n = n0 + wn + (nt << 5) + l31;
        if constexpr (MODE == 1) {
#pragma unroll
            for (int r = 0; r < 16; ++r) {
                const int m = m0 + wm + ROWMAP(r, hh);
                Cout[(size_t)m * E_ + n] = acc1[nt][r];
            }
        } else {
            const int hd = n >> 6, d = n & 63;
            const int b = m0 >> 11;             // block never crosses batch
            u16 vb16[16];
#pragma unroll
            for (int r = 0; r < 16; ++r) {
                const int s = (m0 + wm + ROWMAP(r, hh)) & (S_ - 1);
                const size_t ib = (((size_t)(b * H_ + hd) << 11) + s) * D_ + d;
                const float kv = acc1[nt][r];   // SC2 already folded
                const f16 kh = (f16)kv;
                Khg[ib] = f16bits(kh);
                Klg[ib] = f16bits((f16)(kv - (float)kh));
                const f16 vh = (f16)acc2[nt][r];
                vb16[r] = f16bits(vh);
                Vhg[ib] = vb16[r];
            }
            const size_t vtb = ((size_t)(b * H_ + hd) * D_ + d) << 11;
#pragma unroll
            for (int g = 0; g < 4; ++g) {
                const int s0 = ((m0 + wm) & (S_ - 1)) + (g << 3) + (hh << 2);
                *(uint2*)&Vtg[vtb + s0] =
                    make_uint2(pack2(vb16[4 * g], vb16[4 * g + 1]),
                               pack2(vb16[4 * g + 2], vb16[4 * g + 3]));
            }
        }
    }
}

// ============================================================================
// Attention (R3/R10-exact, best measured 65.0-65.8us; FROZEN).
// Session evidence: T15 interleave (R4, -4%), pair-rounds (R8, 0), indep.
// blocks (R9, 0), t-splits (R2/R6, negative), counted-vmcnt pipeline (R12,
// -7%) — all rearrangements land 65-69us. The dependent chain (ds_read ->
// St MFMA -> softmax VALU -> PV MFMA) at 2 waves/SIMD is the structural
// floor; __syncthreads' vmcnt drain is NOT the cost (R12 refuted).
// logits2 = Ks@V^T, base-2 online softmax, O = P@V. All fp16.
// 512 thr / 8 waves; 256 s-rows/block; grid (8,32)=256 blocks.
// O^T orientation: PV computes D[m=d][n=s], A = Vt (staged), B = P^T built
// in-register via 16 cvt_pkrtz + 8 v_permlane32_swap_b32 (T12); per-lane
// alpha/linv. sV double-buffered (2 x [Vh|Vt] = 33.3KB static), depth-1
// register prefetch, 1 barrier/iter.
// ============================================================================
#define CSA 520             // (64+1)*8 u16
#define VA  (8 * CSA)       // one V array: 4160 u16

__global__ __launch_bounds__(512, 2)
void attn_mfma(const u16* __restrict__ Kh, const u16* __restrict__ Kl,
               const u16* __restrict__ Vh, const u16* __restrict__ Vt,
               u16* __restrict__ Obuf)
{
    __shared__ u16 sV[4 * VA];          // [buf][Vh | Vt], double-buffered

    const int tid = threadIdx.x;
    const int w = tid >> 6, l31 = tid & 31, hh = (tid >> 5) & 1;
    const int bh = blockIdx.y;
    const int sbase = blockIdx.x * 256 + (w << 5);
    const int sg = sbase + l31;

    // K fragments (SC2 pre-folded): B[n=s][k=d], hi/lo, loop-invariant
    f16x8 kfh[4], kfl[4];
    {
        const size_t kb = ((size_t)bh * S_ + sg) * D_;
#pragma unroll
        for (int ks = 0; ks < 4; ++ks) {
            const int db = (ks << 4) + (hh << 3);
            kfh[ks] = *(const f16x8*)(Kh + kb + db);
            kfl[ks] = *(const f16x8*)(Kl + kb + db);
        }
    }

    f32x16 oacc[2];                     // O^T: row d = ROWMAP+32nt, col s = l31
#pragma unroll
    for (int r = 0; r < 16; ++r) { oacc[0][r] = 0.f; oacc[1][r] = 0.f; }
    float m_i = -INFINITY, l_i = 0.f;

    const int rr = tid >> 3, cc = tid & 7;     // staging: row 0..63, chunk 0..7
    const size_t gn = ((size_t)bh * S_ + rr) * D_ + (cc << 3);
    const size_t gt = ((size_t)bh * D_ + rr) * S_ + (cc << 3);
    const int slo = cc * CSA + rr * 8;

    f16x8 pv[2];
    auto load_tile = [&](int it2) {
        const size_t t0 = (size_t)it2 << 6;
        pv[0] = *(const f16x8*)(Vh + gn + t0 * D_);
        pv[1] = *(const f16x8*)(Vt + gt + t0);
    };

    load_tile(0);
    *(f16x8*)&sV[slo] = pv[0];
    *(f16x8*)&sV[VA + slo] = pv[1];
    __syncthreads();

    for (int it = 0; it < 32; ++it) {
        const int vb = (it & 1) * (2 * VA);
        const int nb = ((it + 1) & 1) * (2 * VA);
        if (it + 1 < 32) load_tile(it + 1);    // global->reg prefetch

        // St[t][s] = sum_d V[t][d]*Ks[s][d]  (2-pass, dual chains)
        f32x16 sta[2], stb[2];
#pragma unroll
        for (int r = 0; r < 16; ++r) {
            sta[0][r] = 0.f; sta[1][r] = 0.f;
            stb[0][r] = 0.f; stb[1][r] = 0.f;
        }
#pragma unroll
        for (int ks = 0; ks < 4; ++ks) {
            const int ch = (ks << 1) + hh;
#pragma unroll
            for (int mt = 0; mt < 2; ++mt) {
                const f16x8 av = *(const f16x8*)&sV[vb + ch * CSA + ((mt << 5) + l31) * 8];
                sta[mt] = mfma_h(av, kfh[ks], sta[mt]);
                stb[mt] = mfma_h(av, kfl[ks], stb[mt]);
            }
        }
#pragma unroll
        for (int mt = 0; mt < 2; ++mt)
#pragma unroll
            for (int r = 0; r < 16; ++r) sta[mt][r] += stb[mt][r];

        // Online softmax (base 2) over t for col s = l31
        float tmax = -INFINITY;
#pragma unroll
        for (int mt = 0; mt < 2; ++mt)
#pragma unroll
            for (int r = 0; r < 16; ++r) tmax = fmaxf(tmax, sta[mt][r]);
        tmax = fmaxf(tmax, __shfl_xor(tmax, 32));
        const float mnew = fmaxf(m_i, tmax);
        const float alpha = __builtin_amdgcn_exp2f(m_i - mnew);  // first tile: 0
        m_i = mnew;
        // cmask==0  =>  mnew==m_i for every lane  =>  alpha==1: skip all.
        const unsigned long long cmask = __ballot(tmax >= mnew - 30.f);

        if (cmask) {
            float rsum = 0.f;
#pragma unroll
            for (int mt = 0; mt < 2; ++mt)
#pragma unroll
                for (int r = 0; r < 16; ++r) {
                    const float p = __builtin_amdgcn_exp2f(sta[mt][r] - mnew);
                    sta[mt][r] = p;
                    rsum += p;
                }
            rsum += __shfl_xor(rsum, 32);
            l_i = l_i * alpha + rsum;

            // alpha rescale: per-lane (oacc col = s = l31)
#pragma unroll
            for (int r = 0; r < 16; ++r) { oacc[0][r] *= alpha; oacc[1][r] *= alpha; }

            // pack P to fp16: pa[mt][q] = (t0,t0+1), pb = (t0+2,t0+3),
            // t0 = 32mt+8q+4hh (own hh)
            unsigned pa[2][4], pb[2][4];
#pragma unroll
            for (int mt = 0; mt < 2; ++mt)
#pragma unroll
                for (int q = 0; q < 4; ++q) {
                    pa[mt][q] = pkrtz(sta[mt][4 * q + 0], sta[mt][4 * q + 1]);
                    pb[mt][q] = pkrtz(sta[mt][4 * q + 2], sta[mt][4 * q + 3]);
                }

            // PV: O^T[d][s] += Vt[d][t] * P^T[t][s], 4 chunks of K=16
#pragma unroll
            for (int ks = 0; ks < 4; ++ks) {
                const int mt = ks >> 1, kk = ks & 1;
                unsigned w0 = pa[mt][2 * kk], w2v = pa[mt][2 * kk + 1];
                pl32swap(w0, w2v);
                unsigned w1 = pb[mt][2 * kk], w3v = pb[mt][2 * kk + 1];
                pl32swap(w1, w3v);
                union { unsigned u[4]; f16x8 v; } bw;
                bw.u[0] = w0; bw.u[1] = w1; bw.u[2] = w2v; bw.u[3] = w3v;
                const int ch = (ks << 1) + hh;
#pragma unroll
                for (int nt = 0; nt < 2; ++nt) {
                    const f16x8 vtf = *(const f16x8*)&sV[vb + VA + ch * CSA + ((nt << 5) + l31) * 8];
                    oacc[nt] = mfma_h(vtf, bw.v, oacc[nt]);
                }
            }
        }

        if (it + 1 < 32) {                     // stage next tile into other buf
            *(f16x8*)&sV[nb + slo] = pv[0];
            *(f16x8*)&sV[nb + VA + slo] = pv[1];
        }
        __syncthreads();
    }

    // Epilogue: per-lane normalize (l_i is per-s = per-lane), store O fp16 [M,E]
    const float linv = (l_i > 0.f) ? (1.0f / l_i) : 0.f;
    const int b = bh >> 4;
    const int hd = bh & 15;
    u16* Or = Obuf + ((size_t)b * S_ + sg) * E_ + (hd << 6);
#pragma unroll
    for (int nt = 0; nt < 2; ++nt)
#pragma unroll
        for (int q = 0; q < 4; ++q) {
            const int d0 = (nt << 5) + (q << 3) + (hh << 2);
            u16 c[4];
#pragma unroll
            for (int j = 0; j < 4; ++j)
                c[j] = f16bits((f16)(oacc[nt][4 * q + j] * linv));
            *(uint2*)&Or[d0] = make_uint2(pack2(c[0], c[1]), pack2(c[2], c[3]));
        }
}

// ============================================================================
// Workspace (~58 MB):
//   0M Xh | 8M Xl (aliased by Obuf after gemm_kv) | 16M Wkh | 18M Wkl
//   20M Wvh | 22M Wvl | 24M Woh | 26M Kh | 34M Kl | 42M Vh | 50M Vt
// ============================================================================
extern "C" void kernel_launch(void* const* d_in, const int* in_sizes, int n_in,
                              void* d_out, int out_size, void* d_ws, size_t ws_size,
                              hipStream_t stream)
{
    (void)in_sizes; (void)n_in; (void)out_size; (void)ws_size;
    const float* x  = (const float*)d_in[0];
    // d_in[1] = Wq: computed-but-unused in reference; skipped.
    const float* Wk = (const float*)d_in[2];
    const float* Wv = (const float*)d_in[3];
    const float* Wo = (const float*)d_in[4];
    float* out = (float*)d_out;

    char* ws = (char*)d_ws;
    const size_t MB = 1u << 20;
    u16* Xh  = (u16*)(ws + 0 * MB);
    u16* Xl  = (u16*)(ws + 8 * MB);
    u16* Wkh = (u16*)(ws + 16 * MB);
    u16* Wkl = (u16*)(ws + 18 * MB);
    u16* Wvh = (u16*)(ws + 20 * MB);
    u16* Wvl = (u16*)(ws + 22 * MB);
    u16* Woh = (u16*)(ws + 24 * MB);
    u16* Kh  = (u16*)(ws + 26 * MB);
    u16* Kl  = (u16*)(ws + 34 * MB);
    u16* Vh  = (u16*)(ws + 42 * MB);
    u16* Vt  = (u16*)(ws + 50 * MB);
    u16* Obuf = Xl;        // x-lo dead after gemm_kv

    // Dynamic-LDS sizes (gemms only; attn is static 33.3KB).
    const int lds0 = 6 * (8 * CSB) * (int)sizeof(u16);        // 99072 B
    const int lds1 = 2 * 2 * (16 * CSB) * (int)sizeof(u16);   // 132096 B (dbuf)
    static bool attr_done = false;
    if (!attr_done) {
        hipFuncSetAttribute(reinterpret_cast<const void*>(&gemm_f<0>),
                            hipFuncAttributeMaxDynamicSharedMemorySize, lds0);
        hipFuncSetAttribute(reinterpret_cast<const void*>(&gemm_f<1>),
                            hipFuncAttributeMaxDynamicSharedMemorySize, lds1);
        attr_done = true;
    }

    convert_split<<<7168, 256, 0, stream>>>(x, Wk, Wv, Wo,
                                            Xh, Xl, Wkh, Wkl, Wvh, Wvl, Woh);
    gemm_f<0><<<dim3(E_ / 128, M_ / 128), 1024, lds0, stream>>>(
        Xh, Xl, Wkh, Wkl, Wvh, Wvl, Kh, Kl, Vh, Vt, nullptr);
    attn_mfma<<<dim3(S_ / 256, B_ * H_), 512, 0, stream>>>(Kh, Kl, Vh, Vt, Obuf);
    gemm_f<1><<<dim3(E_ / 128, M_ / 128), 1024, lds1, stream>>>(
        Obuf, Obuf, Woh, Woh, Woh, Woh,
        nullptr, nullptr, nullptr, nullptr, out);
}